// Round 3
// baseline (2997.648 us; speedup 1.0000x reference)
//
#include <hip/hip_runtime.h>
#include <hip/hip_bf16.h>

// CausalSelfAttention: B=4, N=2048, D=1024, H=16, HD=64
// Interface dtype: fp32 in / fp32 out (H3 — the only hypothesis consistent with
// all three observed failures: R1 NaN = fp32-read-as-bf16; R2 err 5.34 =
// bf16-written-parsed-as-fp32; R0 err 4.125 = max|ref| vs zeros).
// Internals: kqv & sa stored bf16 (exactly 64 MiB of d_ws), fp32 accumulate.
//
// Pipeline:
//   1) kqv[8192,3072] = x[8192,1024] @ Wkqv^T[3072,1024] + bkqv      (gemm_bt)
//   2) attn: per (b,h), flash-style causal, lane=query, Q/O in regs   (attn)
//   3) out = sa @ Wproj^T + bproj                                     (gemm_bt)

#define NSEQ 2048
#define NHEAD 16
#define DMODEL 1024
#define KQV_COLS 3072

__device__ __forceinline__ float bf2f(unsigned short u) {
    union { unsigned int i; float f; } v;
    v.i = ((unsigned int)u) << 16;
    return v.f;
}
__device__ __forceinline__ unsigned short f2bf(float f) {
    unsigned int x = __float_as_uint(f);
    unsigned int r = x + 0x7fffu + ((x >> 16) & 1u);  // RNE
    return (unsigned short)(r >> 16);
}

// C[M,Nc] = A[M,K] @ B[Nc,K]^T + bias[Nc]. B/bias fp32. A bf16 or fp32 (template),
// C bf16 or fp32 (template). fp32 accumulate. 128x128 tile, 256 threads,
// 8x8 micro-tile/thread, K-tile 16.
template <bool A_BF16, bool C_F32>
__global__ __launch_bounds__(256) void gemm_bt(
    const void* __restrict__ Av,
    const float* __restrict__ B,
    const float* __restrict__ bias,
    void* __restrict__ Cv,
    int M, int Nc, int K)
{
    __shared__ float As[16][132];  // [k][m], stride 132 floats (16B-aligned rows)
    __shared__ float Bs[16][132];  // [k][n]

    const int t  = threadIdx.x;
    const int tx = t & 15;   // n-dir
    const int ty = t >> 4;   // m-dir
    const int m0 = blockIdx.y * 128;
    const int n0 = blockIdx.x * 128;
    const int lr = t >> 1;         // 0..127 tile row for loads
    const int lk = (t & 1) << 3;   // 0 or 8

    float acc[8][8];
#pragma unroll
    for (int i = 0; i < 8; ++i)
#pragma unroll
        for (int j = 0; j < 8; ++j) acc[i][j] = 0.f;

    const unsigned short* pa_u = (const unsigned short*)Av + (size_t)(m0 + lr) * K + lk;
    const float*          pa_f = (const float*)Av + (size_t)(m0 + lr) * K + lk;
    const float*          pb   = B + (size_t)(n0 + lr) * K + lk;

    for (int k0 = 0; k0 < K; k0 += 16) {
        float av[8], bv[8];
        if (A_BF16) {
            ushort4 a0 = *(const ushort4*)(pa_u + k0);
            ushort4 a1 = *(const ushort4*)(pa_u + k0 + 4);
            av[0] = bf2f(a0.x); av[1] = bf2f(a0.y); av[2] = bf2f(a0.z); av[3] = bf2f(a0.w);
            av[4] = bf2f(a1.x); av[5] = bf2f(a1.y); av[6] = bf2f(a1.z); av[7] = bf2f(a1.w);
        } else {
            float4 a0 = *(const float4*)(pa_f + k0);
            float4 a1 = *(const float4*)(pa_f + k0 + 4);
            av[0] = a0.x; av[1] = a0.y; av[2] = a0.z; av[3] = a0.w;
            av[4] = a1.x; av[5] = a1.y; av[6] = a1.z; av[7] = a1.w;
        }
        {
            float4 b0 = *(const float4*)(pb + k0);
            float4 b1 = *(const float4*)(pb + k0 + 4);
            bv[0] = b0.x; bv[1] = b0.y; bv[2] = b0.z; bv[3] = b0.w;
            bv[4] = b1.x; bv[5] = b1.y; bv[6] = b1.z; bv[7] = b1.w;
        }
        __syncthreads();
#pragma unroll
        for (int c = 0; c < 8; ++c) { As[lk + c][lr] = av[c]; Bs[lk + c][lr] = bv[c]; }
        __syncthreads();
#pragma unroll
        for (int kk = 0; kk < 16; ++kk) {
            float a[8], bb[8];
            *(float4*)&a[0]  = *(const float4*)&As[kk][ty * 8];
            *(float4*)&a[4]  = *(const float4*)&As[kk][ty * 8 + 4];
            *(float4*)&bb[0] = *(const float4*)&Bs[kk][tx * 8];
            *(float4*)&bb[4] = *(const float4*)&Bs[kk][tx * 8 + 4];
#pragma unroll
            for (int i = 0; i < 8; ++i)
#pragma unroll
                for (int j = 0; j < 8; ++j)
                    acc[i][j] = fmaf(a[i], bb[j], acc[i][j]);
        }
    }

    float bn[8];
#pragma unroll
    for (int j = 0; j < 8; ++j) bn[j] = bias[n0 + tx * 8 + j];

#pragma unroll
    for (int i = 0; i < 8; ++i) {
        const size_t row = (size_t)(m0 + ty * 8 + i) * Nc + n0 + tx * 8;
        if (C_F32) {
            float4 w0, w1;
            w0.x = acc[i][0] + bn[0]; w0.y = acc[i][1] + bn[1];
            w0.z = acc[i][2] + bn[2]; w0.w = acc[i][3] + bn[3];
            w1.x = acc[i][4] + bn[4]; w1.y = acc[i][5] + bn[5];
            w1.z = acc[i][6] + bn[6]; w1.w = acc[i][7] + bn[7];
            float* pc = (float*)Cv + row;
            *(float4*)pc       = w0;
            *(float4*)(pc + 4) = w1;
        } else {
            ushort4 w0, w1;
            w0.x = f2bf(acc[i][0] + bn[0]); w0.y = f2bf(acc[i][1] + bn[1]);
            w0.z = f2bf(acc[i][2] + bn[2]); w0.w = f2bf(acc[i][3] + bn[3]);
            w1.x = f2bf(acc[i][4] + bn[4]); w1.y = f2bf(acc[i][5] + bn[5]);
            w1.z = f2bf(acc[i][6] + bn[6]); w1.w = f2bf(acc[i][7] + bn[7]);
            unsigned short* pc = (unsigned short*)Cv + row;
            *(ushort4*)pc       = w0;
            *(ushort4*)(pc + 4) = w1;
        }
    }
}

// Flash-style causal attention. grid (N/256, B*H), block 256 (4 waves).
// Wave w owns 64 queries; lane = query. Q[64]/O[64] in regs; K/V tiles in LDS,
// read via uniform-address broadcast. Finite -1e30 sentinel (no inf arithmetic).
// kqv layout: [b*N+n, h*192 + e], e: k=0..63, q=64..127, v=128..191.  All bf16.
__global__ __launch_bounds__(256) void attn(
    const unsigned short* __restrict__ kqv,
    unsigned short* __restrict__ sa)
{
    __shared__ float Ks[64][64];
    __shared__ float Vs[64][64];

    const int t    = threadIdx.x;
    const int w    = t >> 6;
    const int lane = t & 63;
    const int bh   = blockIdx.y;
    const int b    = bh >> 4;
    const int h    = bh & 15;
    const int qt_w = blockIdx.x * 4 + w;   // this wave's 64-query tile index
    const int qi   = qt_w * 64 + lane;     // this lane's query row

    const float MASKV = -1e30f;

    const size_t qrow = ((size_t)b * NSEQ + qi) * KQV_COLS + h * 192;
    float q[64];
#pragma unroll
    for (int u = 0; u < 16; ++u) {
        ushort4 v4 = *(const ushort4*)(kqv + qrow + 64 + u * 4);
        q[u * 4 + 0] = bf2f(v4.x); q[u * 4 + 1] = bf2f(v4.y);
        q[u * 4 + 2] = bf2f(v4.z); q[u * 4 + 3] = bf2f(v4.w);
    }
    float o[64];
#pragma unroll
    for (int d = 0; d < 64; ++d) o[d] = 0.f;
    float m = MASKV, l = 0.f;

    const int kt_last = blockIdx.x * 4 + 3;  // uniform across block (barrier-safe)
    for (int kt = 0; kt <= kt_last; ++kt) {
        __syncthreads();
#pragma unroll
        for (int i = 0; i < 4; ++i) {
            int p = t + i * 256;        // quad index 0..1023
            int r = p >> 4;             // tile row 0..63
            int d = (p & 15) << 2;      // 0..60
            const size_t krow = ((size_t)b * NSEQ + kt * 64 + r) * KQV_COLS + h * 192;
            ushort4 k4 = *(const ushort4*)(kqv + krow + d);
            Ks[r][d + 0] = bf2f(k4.x); Ks[r][d + 1] = bf2f(k4.y);
            Ks[r][d + 2] = bf2f(k4.z); Ks[r][d + 3] = bf2f(k4.w);
            ushort4 v4 = *(const ushort4*)(kqv + krow + 128 + d);
            Vs[r][d + 0] = bf2f(v4.x); Vs[r][d + 1] = bf2f(v4.y);
            Vs[r][d + 2] = bf2f(v4.z); Vs[r][d + 3] = bf2f(v4.w);
        }
        __syncthreads();
        if (kt > qt_w) continue;  // beyond causal range for this wave; barriers stay matched

        const int kbase = kt * 64;
#pragma unroll
        for (int c0 = 0; c0 < 64; c0 += 16) {
            float s[16];
#pragma unroll
            for (int j = 0; j < 16; ++j) {
                const int kj = c0 + j;
                float acc = 0.f;
#pragma unroll
                for (int d4 = 0; d4 < 64; d4 += 4) {
                    float4 kv = *(const float4*)&Ks[kj][d4];
                    acc = fmaf(q[d4 + 0], kv.x, acc);
                    acc = fmaf(q[d4 + 1], kv.y, acc);
                    acc = fmaf(q[d4 + 2], kv.z, acc);
                    acc = fmaf(q[d4 + 3], kv.w, acc);
                }
                s[j] = (kbase + kj <= qi) ? acc * 0.125f : MASKV;
            }
            float mx = s[0];
#pragma unroll
            for (int j = 1; j < 16; ++j) mx = fmaxf(mx, s[j]);
            const float m_new = fmaxf(m, mx);
            if (m_new == MASKV) continue;  // chunk fully masked & nothing seen yet
            const float alpha = __expf(m - m_new);  // m==MASKV -> underflows to 0
            float sum = 0.f;
#pragma unroll
            for (int j = 0; j < 16; ++j) { s[j] = __expf(s[j] - m_new); sum += s[j]; }
            l = l * alpha + sum;
            m = m_new;
#pragma unroll
            for (int d = 0; d < 64; ++d) o[d] *= alpha;
#pragma unroll
            for (int j = 0; j < 16; ++j) {
                const float pj = s[j];
#pragma unroll
                for (int d4 = 0; d4 < 64; d4 += 4) {
                    float4 vv = *(const float4*)&Vs[c0 + j][d4];
                    o[d4 + 0] = fmaf(pj, vv.x, o[d4 + 0]);
                    o[d4 + 1] = fmaf(pj, vv.y, o[d4 + 1]);
                    o[d4 + 2] = fmaf(pj, vv.z, o[d4 + 2]);
                    o[d4 + 3] = fmaf(pj, vv.w, o[d4 + 3]);
                }
            }
        }
    }

    const float inv = 1.f / l;  // l >= exp(0)=1 (diagonal always unmasked)
    const size_t orow = ((size_t)b * NSEQ + qi) * DMODEL + h * 64;
#pragma unroll
    for (int u = 0; u < 16; ++u) {
        ushort4 w4;
        w4.x = f2bf(o[u * 4 + 0] * inv);
        w4.y = f2bf(o[u * 4 + 1] * inv);
        w4.z = f2bf(o[u * 4 + 2] * inv);
        w4.w = f2bf(o[u * 4 + 3] * inv);
        *(ushort4*)(sa + orow + u * 4) = w4;
    }
}

extern "C" void kernel_launch(void* const* d_in, const int* in_sizes, int n_in,
                              void* d_out, int out_size, void* d_ws, size_t ws_size,
                              hipStream_t stream) {
    const float* x     = (const float*)d_in[0];  // [4,2048,1024]
    const float* Wkqv  = (const float*)d_in[1];  // [16,192,1024]
    const float* bkqv  = (const float*)d_in[2];  // [16,192]
    const float* Wproj = (const float*)d_in[3];  // [1024,1024]
    const float* bproj = (const float*)d_in[4];  // [1024]
    float* out = (float*)d_out;                  // [4,2048,1024] fp32

    unsigned short* kqv = (unsigned short*)d_ws;          // [8192,3072] bf16 (50.3MB)
    unsigned short* sa  = kqv + (size_t)8192 * KQV_COLS;  // [8192,1024] bf16 (16.8MB)

    // 1) kqv = x @ Wkqv^T + bkqv   (M=8192, Nc=3072, K=1024): A fp32, C bf16
    gemm_bt<false, false><<<dim3(KQV_COLS / 128, 8192 / 128), 256, 0, stream>>>(
        x, Wkqv, bkqv, kqv, 8192, KQV_COLS, 1024);
    // 2) attention -> sa (bf16 -> bf16)
    attn<<<dim3(NSEQ / 256, 4 * NHEAD), 256, 0, stream>>>(kqv, sa);
    // 3) out = sa @ Wproj^T + bproj (M=8192, Nc=1024, K=1024): A bf16, C fp32
    gemm_bt<true, true><<<dim3(DMODEL / 128, 8192 / 128), 256, 0, stream>>>(
        sa, Wproj, bproj, out, 8192, DMODEL, 1024);
}